// Round 6
// baseline (13742.412 us; speedup 1.0000x reference)
//
#include <hip/hip_runtime.h>
#include <math.h>

#define BATCH   131072
#define IN_F    80
#define EMB     64
#define NE      16
#define RANK    8
#define UDIM    16
#define NCLS    10
#define NUSERS  1000

// ---- workspace layout (bytes) ----
#define OFF_H      0ull                 // BATCH*64 f32      = 33554432
#define OFF_A      33554432ull          // NUSERS*16*64 f32  =  4096000
#define OFF_TOPE   37650432ull          // 2*BATCH int
#define OFF_TOPW   38699008ull          // 2*BATCH f32
#define OFF_PAIRB  39747584ull          // 2*BATCH int
#define OFF_PAIRW  40796160ull          // 2*BATCH f32
#define OFF_HIST   41844736ull
#define OFF_OFFS   41845760ull
#define OFF_CUR    41846784ull

__device__ __forceinline__ float gelu_f(float v) {
    return 0.5f * v * (1.0f + erff(v * 0.70710678118654752440f));
}
__device__ __forceinline__ float4 gelu4(float4 v) {
    v.x = gelu_f(v.x); v.y = gelu_f(v.y); v.z = gelu_f(v.z); v.w = gelu_f(v.w);
    return v;
}
__device__ __forceinline__ float4 sfma4(float s, float4 w, float4 a) {
    a.x = fmaf(s, w.x, a.x); a.y = fmaf(s, w.y, a.y);
    a.z = fmaf(s, w.z, a.z); a.w = fmaf(s, w.w, a.w);
    return a;
}
__device__ __forceinline__ float4 ffma4(float4 v, float4 w, float4 a) {
    a.x = fmaf(v.x, w.x, a.x); a.y = fmaf(v.y, w.y, a.y);
    a.z = fmaf(v.z, w.z, a.z); a.w = fmaf(v.w, w.w, a.w);
    return a;
}
__device__ __forceinline__ float4 add4(float4 a, float4 b) {
    a.x += b.x; a.y += b.y; a.z += b.z; a.w += b.w; return a;
}
__device__ __forceinline__ float4 ln4(float4 z, float mu, float inv, float4 g, float4 bb) {
    float4 r;
    r.x = fmaf((z.x - mu) * inv, g.x, bb.x);
    r.y = fmaf((z.y - mu) * inv, g.y, bb.y);
    r.z = fmaf((z.z - mu) * inv, g.z, bb.z);
    r.w = fmaf((z.w - mu) * inv, g.w, bb.w);
    return r;
}

#define FMA16Z(S, WB) do { \
    z0 = sfma4((S), (WB)[0],  z0); z1 = sfma4((S), (WB)[1],  z1); \
    z2 = sfma4((S), (WB)[2],  z2); z3 = sfma4((S), (WB)[3],  z3); \
    z4 = sfma4((S), (WB)[4],  z4); z5 = sfma4((S), (WB)[5],  z5); \
    z6 = sfma4((S), (WB)[6],  z6); z7 = sfma4((S), (WB)[7],  z7); \
    z8 = sfma4((S), (WB)[8],  z8); z9 = sfma4((S), (WB)[9],  z9); \
    za = sfma4((S), (WB)[10], za); zb = sfma4((S), (WB)[11], zb); \
    zc = sfma4((S), (WB)[12], zc); zd = sfma4((S), (WB)[13], zd); \
    ze = sfma4((S), (WB)[14], ze); zf = sfma4((S), (WB)[15], zf); } while (0)
#define FMA16Y(S, WB) do { \
    y0 = sfma4((S), (WB)[0],  y0); y1 = sfma4((S), (WB)[1],  y1); \
    y2 = sfma4((S), (WB)[2],  y2); y3 = sfma4((S), (WB)[3],  y3); \
    y4 = sfma4((S), (WB)[4],  y4); y5 = sfma4((S), (WB)[5],  y5); \
    y6 = sfma4((S), (WB)[6],  y6); y7 = sfma4((S), (WB)[7],  y7); \
    y8 = sfma4((S), (WB)[8],  y8); y9 = sfma4((S), (WB)[9],  y9); \
    ya = sfma4((S), (WB)[10], ya); yb = sfma4((S), (WB)[11], yb); \
    yc = sfma4((S), (WB)[12], yc); yd = sfma4((S), (WB)[13], yd); \
    ye = sfma4((S), (WB)[14], ye); yf = sfma4((S), (WB)[15], yf); } while (0)

// ---------------- A[u][e][d] = sum_r gU[e][d][r] * (sum_dd ut[u][dd]*gV[e][dd][r]) ----------------
__global__ void k_prep(const float* __restrict__ gU, const float* __restrict__ gV,
                       const float* __restrict__ ut, float* __restrict__ A)
{
    int idx = blockIdx.x * 256 + threadIdx.x;
    if (idx >= NUSERS * NE) return;
    int u = idx / NE, e = idx - u * NE;

    const float4* up = (const float4*)(ut + (size_t)u * UDIM);
    float4 u0 = up[0], u1 = up[1], u2 = up[2], u3 = up[3];

    float4 va = make_float4(0.f, 0.f, 0.f, 0.f);
    float4 vb = make_float4(0.f, 0.f, 0.f, 0.f);
    const float4* gv4 = (const float4*)gV;
#define UVSTEP(UD, DD) do { \
        float4 g0 = gv4[(e * UDIM + (DD)) * 2 + 0]; \
        float4 g1 = gv4[(e * UDIM + (DD)) * 2 + 1]; \
        va = sfma4((UD), g0, va); vb = sfma4((UD), g1, vb); } while (0)
    UVSTEP(u0.x, 0);  UVSTEP(u0.y, 1);  UVSTEP(u0.z, 2);  UVSTEP(u0.w, 3);
    UVSTEP(u1.x, 4);  UVSTEP(u1.y, 5);  UVSTEP(u1.z, 6);  UVSTEP(u1.w, 7);
    UVSTEP(u2.x, 8);  UVSTEP(u2.y, 9);  UVSTEP(u2.z, 10); UVSTEP(u2.w, 11);
    UVSTEP(u3.x, 12); UVSTEP(u3.y, 13); UVSTEP(u3.z, 14); UVSTEP(u3.w, 15);
#undef UVSTEP

    const float4* gu4 = (const float4*)gU;
    float* Ao = A + ((size_t)u * NE + e) * EMB;
    for (int d = 0; d < EMB; ++d) {
        float4 q0 = gu4[(e * EMB + d) * 2 + 0];
        float4 q1 = gu4[(e * EMB + d) * 2 + 1];
        float a = 0.0f;
        a = fmaf(q0.x, va.x, a); a = fmaf(q0.y, va.y, a);
        a = fmaf(q0.z, va.z, a); a = fmaf(q0.w, va.w, a);
        a = fmaf(q1.x, vb.x, a); a = fmaf(q1.y, vb.y, a);
        a = fmaf(q1.z, vb.z, a); a = fmaf(q1.w, vb.w, a);
        Ao[d] = a;
    }
}

// ---------------- fused backbone + gate + top2, all named regs, R4 allocator regime ----------------
__global__ __launch_bounds__(128) void k_bbgate(
    const float* __restrict__ x, const int* __restrict__ uid,
    const float* __restrict__ w1, const float* __restrict__ b1,
    const float* __restrict__ w2, const float* __restrict__ b2,
    const float* __restrict__ gam, const float* __restrict__ bet,
    const float* __restrict__ A, const float* __restrict__ gb,
    float* __restrict__ h_out,
    int* __restrict__ top_e, float* __restrict__ top_w, int* __restrict__ hist)
{
    __shared__ __align__(16) float4 s_w1[IN_F * 16];   // 20 KB  [d][k4]
    __shared__ __align__(16) float4 s_w2[EMB * 16];    // 16 KB
    __shared__ __align__(16) float4 s_b1[16], s_b2[16], s_ga[16], s_be[16];
    __shared__ float s_gb[NE];
    __shared__ int s_hist[NE];

    const int tid = threadIdx.x;
    {
        const float4* g1 = (const float4*)w1;
        for (int i = tid; i < IN_F * 16; i += 128) s_w1[i] = g1[i];
        const float4* g2 = (const float4*)w2;
        for (int i = tid; i < EMB * 16; i += 128) s_w2[i] = g2[i];
        if (tid < 16) {
            s_b1[tid] = ((const float4*)b1)[tid];
            s_b2[tid] = ((const float4*)b2)[tid];
            s_ga[tid] = ((const float4*)gam)[tid];
            s_be[tid] = ((const float4*)bet)[tid];
        }
        if (tid < NE) { s_gb[tid] = gb[tid]; s_hist[tid] = 0; }
    }
    __syncthreads();

    const int b = blockIdx.x * 128 + tid;

    const float4* xp = (const float4*)(x + (size_t)b * IN_F);
    float4 x00 = xp[0],  x01 = xp[1],  x02 = xp[2],  x03 = xp[3],  x04 = xp[4];
    float4 x05 = xp[5],  x06 = xp[6],  x07 = xp[7],  x08 = xp[8],  x09 = xp[9];
    float4 x10 = xp[10], x11 = xp[11], x12 = xp[12], x13 = xp[13], x14 = xp[14];
    float4 x15 = xp[15], x16 = xp[16], x17 = xp[17], x18 = xp[18], x19 = xp[19];

    // ---- fc1 (80 -> 64), d-outer, fully static ----
    float4 z0 = s_b1[0],  z1 = s_b1[1],  z2 = s_b1[2],  z3 = s_b1[3];
    float4 z4 = s_b1[4],  z5 = s_b1[5],  z6 = s_b1[6],  z7 = s_b1[7];
    float4 z8 = s_b1[8],  z9 = s_b1[9],  za = s_b1[10], zb = s_b1[11];
    float4 zc = s_b1[12], zd = s_b1[13], ze = s_b1[14], zf = s_b1[15];
#define BB1CH(XV, T) do { const float4* wr = s_w1 + (T) * 64; \
        FMA16Z((XV).x, wr); FMA16Z((XV).y, wr + 16); \
        FMA16Z((XV).z, wr + 32); FMA16Z((XV).w, wr + 48); } while (0)
    BB1CH(x00, 0);  BB1CH(x01, 1);  BB1CH(x02, 2);  BB1CH(x03, 3);  BB1CH(x04, 4);
    BB1CH(x05, 5);  BB1CH(x06, 6);  BB1CH(x07, 7);  BB1CH(x08, 8);  BB1CH(x09, 9);
    BB1CH(x10, 10); BB1CH(x11, 11); BB1CH(x12, 12); BB1CH(x13, 13); BB1CH(x14, 14);
    BB1CH(x15, 15); BB1CH(x16, 16); BB1CH(x17, 17); BB1CH(x18, 18); BB1CH(x19, 19);
#undef BB1CH
    z0 = gelu4(z0); z1 = gelu4(z1); z2 = gelu4(z2); z3 = gelu4(z3);
    z4 = gelu4(z4); z5 = gelu4(z5); z6 = gelu4(z6); z7 = gelu4(z7);
    z8 = gelu4(z8); z9 = gelu4(z9); za = gelu4(za); zb = gelu4(zb);
    zc = gelu4(zc); zd = gelu4(zd); ze = gelu4(ze); zf = gelu4(zf);

    // ---- fc2 (64 -> 64), d-outer, fully static ----
    float4 y0 = s_b2[0],  y1 = s_b2[1],  y2 = s_b2[2],  y3 = s_b2[3];
    float4 y4 = s_b2[4],  y5 = s_b2[5],  y6 = s_b2[6],  y7 = s_b2[7];
    float4 y8 = s_b2[8],  y9 = s_b2[9],  ya = s_b2[10], yb = s_b2[11];
    float4 yc = s_b2[12], yd = s_b2[13], ye = s_b2[14], yf = s_b2[15];
#define BB2CH(ZV, T) do { const float4* wr = s_w2 + (T) * 64; \
        FMA16Y((ZV).x, wr); FMA16Y((ZV).y, wr + 16); \
        FMA16Y((ZV).z, wr + 32); FMA16Y((ZV).w, wr + 48); } while (0)
    BB2CH(z0, 0);  BB2CH(z1, 1);  BB2CH(z2, 2);  BB2CH(z3, 3);
    BB2CH(z4, 4);  BB2CH(z5, 5);  BB2CH(z6, 6);  BB2CH(z7, 7);
    BB2CH(z8, 8);  BB2CH(z9, 9);  BB2CH(za, 10); BB2CH(zb, 11);
    BB2CH(zc, 12); BB2CH(zd, 13); BB2CH(ze, 14); BB2CH(zf, 15);
#undef BB2CH
    y0 = gelu4(y0); y1 = gelu4(y1); y2 = gelu4(y2); y3 = gelu4(y3);
    y4 = gelu4(y4); y5 = gelu4(y5); y6 = gelu4(y6); y7 = gelu4(y7);
    y8 = gelu4(y8); y9 = gelu4(y9); ya = gelu4(ya); yb = gelu4(yb);
    yc = gelu4(yc); yd = gelu4(yd); ye = gelu4(ye); yf = gelu4(yf);

    // ---- LayerNorm ----
    float4 sA = add4(add4(add4(y0, y1), add4(y2, y3)), add4(add4(y4, y5), add4(y6, y7)));
    float4 sB = add4(add4(add4(y8, y9), add4(ya, yb)), add4(add4(yc, yd), add4(ye, yf)));
    float4 sS = add4(sA, sB);
    float mu = (sS.x + sS.y + sS.z + sS.w) * (1.0f / 64.0f);
    float4 vv = make_float4(0.f, 0.f, 0.f, 0.f);
#define BBV(Z) do { float4 d4; d4.x = (Z).x - mu; d4.y = (Z).y - mu; d4.z = (Z).z - mu; d4.w = (Z).w - mu; \
                    vv = ffma4(d4, d4, vv); } while (0)
    BBV(y0); BBV(y1); BBV(y2); BBV(y3); BBV(y4); BBV(y5); BBV(y6); BBV(y7);
    BBV(y8); BBV(y9); BBV(ya); BBV(yb); BBV(yc); BBV(yd); BBV(ye); BBV(yf);
#undef BBV
    float var = (vv.x + vv.y + vv.z + vv.w) * (1.0f / 64.0f);
    float inv = 1.0f / sqrtf(var + 1e-5f);
    y0 = ln4(y0, mu, inv, s_ga[0],  s_be[0]);
    y1 = ln4(y1, mu, inv, s_ga[1],  s_be[1]);
    y2 = ln4(y2, mu, inv, s_ga[2],  s_be[2]);
    y3 = ln4(y3, mu, inv, s_ga[3],  s_be[3]);
    y4 = ln4(y4, mu, inv, s_ga[4],  s_be[4]);
    y5 = ln4(y5, mu, inv, s_ga[5],  s_be[5]);
    y6 = ln4(y6, mu, inv, s_ga[6],  s_be[6]);
    y7 = ln4(y7, mu, inv, s_ga[7],  s_be[7]);
    y8 = ln4(y8, mu, inv, s_ga[8],  s_be[8]);
    y9 = ln4(y9, mu, inv, s_ga[9],  s_be[9]);
    ya = ln4(ya, mu, inv, s_ga[10], s_be[10]);
    yb = ln4(yb, mu, inv, s_ga[11], s_be[11]);
    yc = ln4(yc, mu, inv, s_ga[12], s_be[12]);
    yd = ln4(yd, mu, inv, s_ga[13], s_be[13]);
    ye = ln4(ye, mu, inv, s_ga[14], s_be[14]);
    yf = ln4(yf, mu, inv, s_ga[15], s_be[15]);

    {
        float4* ho = (float4*)(h_out + (size_t)b * EMB);
        ho[0] = y0;  ho[1] = y1;  ho[2] = y2;  ho[3] = y3;
        ho[4] = y4;  ho[5] = y5;  ho[6] = y6;  ho[7] = y7;
        ho[8] = y8;  ho[9] = y9;  ho[10] = ya; ho[11] = yb;
        ho[12] = yc; ho[13] = yd; ho[14] = ye; ho[15] = yf;
    }

    // ---- gate + running top-2 (lowest index wins ties) ----
    const int u = uid[b];
    const float4* Ap = (const float4*)(A + (size_t)u * NE * EMB);
    float m0 = -1e30f, m1 = -1e30f;
    int i0 = 0, i1 = 0;
#pragma unroll 1
    for (int e = 0; e < NE; ++e) {
        const float4* ap = Ap + e * 16;
        float4 ac = make_float4(0.f, 0.f, 0.f, 0.f);
        ac = ffma4(y0, ap[0],  ac); ac = ffma4(y1, ap[1],  ac);
        ac = ffma4(y2, ap[2],  ac); ac = ffma4(y3, ap[3],  ac);
        ac = ffma4(y4, ap[4],  ac); ac = ffma4(y5, ap[5],  ac);
        ac = ffma4(y6, ap[6],  ac); ac = ffma4(y7, ap[7],  ac);
        ac = ffma4(y8, ap[8],  ac); ac = ffma4(y9, ap[9],  ac);
        ac = ffma4(ya, ap[10], ac); ac = ffma4(yb, ap[11], ac);
        ac = ffma4(yc, ap[12], ac); ac = ffma4(yd, ap[13], ac);
        ac = ffma4(ye, ap[14], ac); ac = ffma4(yf, ap[15], ac);
        float ge = ((ac.x + ac.y) + (ac.z + ac.w)) + s_gb[e];
        if (ge > m0)      { m1 = m0; i1 = i0; m0 = ge; i0 = e; }
        else if (ge > m1) { m1 = ge; i1 = e; }
    }
    float t = expf(m1 - m0);
    float w0n = 1.0f / (1.0f + t);
    float w1n = t / (1.0f + t);

    top_e[2*b+0] = i0; top_w[2*b+0] = w0n;
    top_e[2*b+1] = i1; top_w[2*b+1] = w1n;
    atomicAdd(&s_hist[i0], 1);
    atomicAdd(&s_hist[i1], 1);
    __syncthreads();
    if (tid < NE) atomicAdd(&hist[tid], s_hist[tid]);
}

// ---------------- tiny exclusive scan ----------------
__global__ void k_scan(const int* __restrict__ hist, int* __restrict__ offs, int* __restrict__ cur)
{
    if (blockIdx.x == 0 && threadIdx.x == 0) {
        int acc = 0;
        for (int e = 0; e < NE; ++e) { offs[e] = acc; cur[e] = acc; acc += hist[e]; }
    }
}

// ---------------- block-aggregated scatter ----------------
__global__ __launch_bounds__(256) void k_scatter(
    const int* __restrict__ top_e, const float* __restrict__ top_w,
    int* __restrict__ cur, int* __restrict__ pair_b, float* __restrict__ pair_w)
{
    __shared__ int lh[NE];
    __shared__ int lbase[NE];
    const int tid = threadIdx.x;
    if (tid < NE) lh[tid] = 0;
    __syncthreads();

    const int b = blockIdx.x * 256 + tid;
    const int e0 = top_e[2*b+0];
    const int e1 = top_e[2*b+1];
    atomicAdd(&lh[e0], 1);
    atomicAdd(&lh[e1], 1);
    __syncthreads();
    if (tid < NE) {
        lbase[tid] = atomicAdd(&cur[tid], lh[tid]);
        lh[tid] = 0;
    }
    __syncthreads();
    int r0 = atomicAdd(&lh[e0], 1);
    int p0 = lbase[e0] + r0;
    pair_b[p0] = b; pair_w[p0] = top_w[2*b+0];
    int r1 = atomicAdd(&lh[e1], 1);
    int p1 = lbase[e1] + r1;
    pair_b[p1] = b; pair_w[p1] = top_w[2*b+1];
}

// ---------------- expert: h in named regs, fc1 d-outer static, LN, fc2 static ----------------
#define EXP_BX 256
__global__ __launch_bounds__(128) void k_expert(
    const float* __restrict__ h,
    const int* __restrict__ pair_b, const float* __restrict__ pair_w,
    const int* __restrict__ hist, const int* __restrict__ offs,
    const float* __restrict__ ew1, const float* __restrict__ eb1,
    const float* __restrict__ eg, const float* __restrict__ ebeta,
    const float* __restrict__ ew2, const float* __restrict__ eb2,
    float* __restrict__ out)
{
    const int e = blockIdx.y;
    const int cnt = hist[e];
    if ((int)(blockIdx.x * 128) >= cnt) return;

    __shared__ __align__(16) float4 s_w1[EMB * 16];    // 16 KB [d][k4]
    __shared__ __align__(16) float4 s_w2[EMB * 3];     // 3 KB  [k][c4] padded 10->12
    __shared__ __align__(16) float4 s_b1[16], s_ga[16], s_be[16], s_b2[3];

    const int tid = threadIdx.x;
    {
        const float4* g1 = (const float4*)(ew1 + (size_t)e * EMB * EMB);
        for (int i = tid; i < EMB * 16; i += 128) s_w1[i] = g1[i];
        float* w2f = (float*)s_w2;
        for (int i = tid; i < EMB * 12; i += 128) {
            int k = i / 12, c = i - k * 12;
            w2f[i] = (c < NCLS) ? ew2[((size_t)e * EMB + k) * NCLS + c] : 0.0f;
        }
        if (tid < 16) {
            s_b1[tid] = ((const float4*)(eb1   + (size_t)e * EMB))[tid];
            s_ga[tid] = ((const float4*)(eg    + (size_t)e * EMB))[tid];
            s_be[tid] = ((const float4*)(ebeta + (size_t)e * EMB))[tid];
        }
        float* b2f = (float*)s_b2;
        if (tid < 12) b2f[tid] = (tid < NCLS) ? eb2[e * NCLS + tid] : 0.0f;
    }
    __syncthreads();

    const int base = offs[e];

    for (int lane = blockIdx.x * 128 + tid; lane < cnt; lane += EXP_BX * 128) {
        const int idx = base + lane;
        const int b = pair_b[idx];
        const float pw = pair_w[idx];

        const float4* hp = (const float4*)(h + (size_t)b * EMB);
        float4 h0 = hp[0],  h1 = hp[1],  h2 = hp[2],  h3 = hp[3];
        float4 h4 = hp[4],  h5 = hp[5],  h6 = hp[6],  h7 = hp[7];
        float4 h8 = hp[8],  h9 = hp[9],  ha = hp[10], hb = hp[11];
        float4 hc = hp[12], hd = hp[13], he = hp[14], hf = hp[15];

        float4 z0 = s_b1[0],  z1 = s_b1[1],  z2 = s_b1[2],  z3 = s_b1[3];
        float4 z4 = s_b1[4],  z5 = s_b1[5],  z6 = s_b1[6],  z7 = s_b1[7];
        float4 z8 = s_b1[8],  z9 = s_b1[9],  za = s_b1[10], zb = s_b1[11];
        float4 zc = s_b1[12], zd = s_b1[13], ze = s_b1[14], zf = s_b1[15];
#define EXCH(HV, T) do { const float4* wr = s_w1 + (T) * 64; \
        FMA16Z((HV).x, wr); FMA16Z((HV).y, wr + 16); \
        FMA16Z((HV).z, wr + 32); FMA16Z((HV).w, wr + 48); } while (0)
        EXCH(h0, 0);  EXCH(h1, 1);  EXCH(h2, 2);  EXCH(h3, 3);
        EXCH(h4, 4);  EXCH(h5, 5);  EXCH(h6, 6);  EXCH(h7, 7);
        EXCH(h8, 8);  EXCH(h9, 9);  EXCH(ha, 10); EXCH(hb, 11);
        EXCH(hc, 12); EXCH(hd, 13); EXCH(he, 14); EXCH(hf, 15);
#undef EXCH
        z0 = gelu4(z0); z1 = gelu4(z1); z2 = gelu4(z2); z3 = gelu4(z3);
        z4 = gelu4(z4); z5 = gelu4(z5); z6 = gelu4(z6); z7 = gelu4(z7);
        z8 = gelu4(z8); z9 = gelu4(z9); za = gelu4(za); zb = gelu4(zb);
        zc = gelu4(zc); zd = gelu4(zd); ze = gelu4(ze); zf = gelu4(zf);

        float4 sA = add4(add4(add4(z0, z1), add4(z2, z3)), add4(add4(z4, z5), add4(z6, z7)));
        float4 sB = add4(add4(add4(z8, z9), add4(za, zb)), add4(add4(zc, zd), add4(ze, zf)));
        float4 sS = add4(sA, sB);
        float mu = (sS.x + sS.y + sS.z + sS.w) * (1.0f / 64.0f);
        float4 vv = make_float4(0.f, 0.f, 0.f, 0.f);
#define EXV(Z) do { float4 d4; d4.x = (Z).x - mu; d4.y = (Z).y - mu; d4.z = (Z).z - mu; d4.w = (Z).w - mu; \
                    vv = ffma4(d4, d4, vv); } while (0)
        EXV(z0); EXV(z1); EXV(z2); EXV(z3); EXV(z4); EXV(z5); EXV(z6); EXV(z7);
        EXV(z8); EXV(z9); EXV(za); EXV(zb); EXV(zc); EXV(zd); EXV(ze); EXV(zf);
#undef EXV
        float var = (vv.x + vv.y + vv.z + vv.w) * (1.0f / 64.0f);
        float inv = 1.0f / sqrtf(var + 1e-5f);
        z0 = ln4(z0, mu, inv, s_ga[0],  s_be[0]);
        z1 = ln4(z1, mu, inv, s_ga[1],  s_be[1]);
        z2 = ln4(z2, mu, inv, s_ga[2],  s_be[2]);
        z3 = ln4(z3, mu, inv, s_ga[3],  s_be[3]);
        z4 = ln4(z4, mu, inv, s_ga[4],  s_be[4]);
        z5 = ln4(z5, mu, inv, s_ga[5],  s_be[5]);
        z6 = ln4(z6, mu, inv, s_ga[6],  s_be[6]);
        z7 = ln4(z7, mu, inv, s_ga[7],  s_be[7]);
        z8 = ln4(z8, mu, inv, s_ga[8],  s_be[8]);
        z9 = ln4(z9, mu, inv, s_ga[9],  s_be[9]);
        za = ln4(za, mu, inv, s_ga[10], s_be[10]);
        zb = ln4(zb, mu, inv, s_ga[11], s_be[11]);
        zc = ln4(zc, mu, inv, s_ga[12], s_be[12]);
        zd = ln4(zd, mu, inv, s_ga[13], s_be[13]);
        ze = ln4(ze, mu, inv, s_ga[14], s_be[14]);
        zf = ln4(zf, mu, inv, s_ga[15], s_be[15]);

        float4 a0 = s_b2[0], a1 = s_b2[1], a2 = s_b2[2];
#define EXF2(ZQ, DB) do { \
        const float4* wr = s_w2 + (DB) * 3; \
        a0 = sfma4((ZQ).x, wr[0],  a0); a1 = sfma4((ZQ).x, wr[1],  a1); a2 = sfma4((ZQ).x, wr[2],  a2); \
        a0 = sfma4((ZQ).y, wr[3],  a0); a1 = sfma4((ZQ).y, wr[4],  a1); a2 = sfma4((ZQ).y, wr[5],  a2); \
        a0 = sfma4((ZQ).z, wr[6],  a0); a1 = sfma4((ZQ).z, wr[7],  a1); a2 = sfma4((ZQ).z, wr[8],  a2); \
        a0 = sfma4((ZQ).w, wr[9],  a0); a1 = sfma4((ZQ).w, wr[10], a1); a2 = sfma4((ZQ).w, wr[11], a2); \
} while (0)
        EXF2(z0, 0);  EXF2(z1, 4);  EXF2(z2, 8);  EXF2(z3, 12);
        EXF2(z4, 16); EXF2(z5, 20); EXF2(z6, 24); EXF2(z7, 28);
        EXF2(z8, 32); EXF2(z9, 36); EXF2(za, 40); EXF2(zb, 44);
        EXF2(zc, 48); EXF2(zd, 52); EXF2(ze, 56); EXF2(zf, 60);
#undef EXF2

        float* ob = out + (size_t)b * NCLS;
        atomicAdd(ob + 0, pw * a0.x);
        atomicAdd(ob + 1, pw * a0.y);
        atomicAdd(ob + 2, pw * a0.z);
        atomicAdd(ob + 3, pw * a0.w);
        atomicAdd(ob + 4, pw * a1.x);
        atomicAdd(ob + 5, pw * a1.y);
        atomicAdd(ob + 6, pw * a1.z);
        atomicAdd(ob + 7, pw * a1.w);
        atomicAdd(ob + 8, pw * a2.x);
        atomicAdd(ob + 9, pw * a2.y);
    }
}

extern "C" void kernel_launch(void* const* d_in, const int* in_sizes, int n_in,
                              void* d_out, int out_size, void* d_ws, size_t ws_size,
                              hipStream_t stream)
{
    (void)in_sizes; (void)n_in; (void)out_size; (void)ws_size;

    const float* x     = (const float*)d_in[0];
    const int*   uid   = (const int*)  d_in[1];
    const float* bb_w1 = (const float*)d_in[2];
    const float* bb_b1 = (const float*)d_in[3];
    const float* bb_w2 = (const float*)d_in[4];
    const float* bb_b2 = (const float*)d_in[5];
    const float* bb_g  = (const float*)d_in[6];
    const float* bb_be = (const float*)d_in[7];
    const float* gU    = (const float*)d_in[8];
    const float* gV    = (const float*)d_in[9];
    const float* gb    = (const float*)d_in[10];
    const float* e_w1  = (const float*)d_in[11];
    const float* e_b1  = (const float*)d_in[12];
    const float* e_g   = (const float*)d_in[13];
    const float* e_be  = (const float*)d_in[14];
    const float* e_w2  = (const float*)d_in[15];
    const float* e_b2  = (const float*)d_in[16];
    const float* ut    = (const float*)d_in[17];

    float* out = (float*)d_out;
    char*  ws  = (char*)d_ws;

    float* h      = (float*)(ws + OFF_H);
    float* A      = (float*)(ws + OFF_A);
    int*   top_e  = (int*)  (ws + OFF_TOPE);
    float* top_w  = (float*)(ws + OFF_TOPW);
    int*   pair_b = (int*)  (ws + OFF_PAIRB);
    float* pair_w = (float*)(ws + OFF_PAIRW);
    int*   hist   = (int*)  (ws + OFF_HIST);
    int*   offs   = (int*)  (ws + OFF_OFFS);
    int*   cur    = (int*)  (ws + OFF_CUR);

    hipMemsetAsync(out, 0, (size_t)BATCH * NCLS * sizeof(float), stream);
    hipMemsetAsync(hist, 0, NE * sizeof(int), stream);

    k_prep<<<(NUSERS * NE + 255) / 256, 256, 0, stream>>>(gU, gV, ut, A);
    k_bbgate<<<BATCH / 128, 128, 0, stream>>>(x, uid, bb_w1, bb_b1, bb_w2, bb_b2,
                                              bb_g, bb_be, A, gb, h, top_e, top_w, hist);
    k_scan<<<1, 64, 0, stream>>>(hist, offs, cur);
    k_scatter<<<BATCH / 256, 256, 0, stream>>>(top_e, top_w, cur, pair_b, pair_w);
    dim3 eg(EXP_BX, NE);
    k_expert<<<eg, 128, 0, stream>>>(h, pair_b, pair_w, hist, offs,
                                     e_w1, e_b1, e_g, e_be, e_w2, e_b2, out);
}

// Round 7
// 3182.697 us; speedup vs baseline: 4.3179x; 4.3179x over previous
//
#include <hip/hip_runtime.h>
#include <math.h>

#define BATCH   131072
#define IN_F    80
#define EMB     64
#define NE      16
#define RANK    8
#define UDIM    16
#define NCLS    10
#define NUSERS  1000

// ---- workspace layout (bytes) ----
#define OFF_H      0ull                 // BATCH*64 f32      = 33554432
#define OFF_A      33554432ull          // NUSERS*16*64 f32  =  4096000
#define OFF_TOPE   37650432ull          // 2*BATCH int
#define OFF_TOPW   38699008ull          // 2*BATCH f32
#define OFF_PAIRB  39747584ull          // 2*BATCH int
#define OFF_PAIRW  40796160ull          // 2*BATCH f32
#define OFF_HIST   41844736ull
#define OFF_OFFS   41845760ull
#define OFF_CUR    41846784ull

__device__ __forceinline__ float gelu_f(float v) {
    return 0.5f * v * (1.0f + erff(v * 0.70710678118654752440f));
}
__device__ __forceinline__ float4 gelu4(float4 v) {
    v.x = gelu_f(v.x); v.y = gelu_f(v.y); v.z = gelu_f(v.z); v.w = gelu_f(v.w);
    return v;
}
__device__ __forceinline__ float4 sfma4(float s, float4 w, float4 a) {
    a.x = fmaf(s, w.x, a.x); a.y = fmaf(s, w.y, a.y);
    a.z = fmaf(s, w.z, a.z); a.w = fmaf(s, w.w, a.w);
    return a;
}
__device__ __forceinline__ float4 ffma4(float4 v, float4 w, float4 a) {
    a.x = fmaf(v.x, w.x, a.x); a.y = fmaf(v.y, w.y, a.y);
    a.z = fmaf(v.z, w.z, a.z); a.w = fmaf(v.w, w.w, a.w);
    return a;
}
__device__ __forceinline__ float4 add4(float4 a, float4 b) {
    a.x += b.x; a.y += b.y; a.z += b.z; a.w += b.w; return a;
}
__device__ __forceinline__ float4 ln4(float4 z, float mu, float inv, float4 g, float4 bb) {
    float4 r;
    r.x = fmaf((z.x - mu) * inv, g.x, bb.x);
    r.y = fmaf((z.y - mu) * inv, g.y, bb.y);
    r.z = fmaf((z.z - mu) * inv, g.z, bb.z);
    r.w = fmaf((z.w - mu) * inv, g.w, bb.w);
    return r;
}

// 16-wide accumulator updates (named z0..zf / y0..yf), weights broadcast from LDS
#define FMA16Z(S, WB) do { \
    z0 = sfma4((S), (WB)[0],  z0); z1 = sfma4((S), (WB)[1],  z1); \
    z2 = sfma4((S), (WB)[2],  z2); z3 = sfma4((S), (WB)[3],  z3); \
    z4 = sfma4((S), (WB)[4],  z4); z5 = sfma4((S), (WB)[5],  z5); \
    z6 = sfma4((S), (WB)[6],  z6); z7 = sfma4((S), (WB)[7],  z7); \
    z8 = sfma4((S), (WB)[8],  z8); z9 = sfma4((S), (WB)[9],  z9); \
    za = sfma4((S), (WB)[10], za); zb = sfma4((S), (WB)[11], zb); \
    zc = sfma4((S), (WB)[12], zc); zd = sfma4((S), (WB)[13], zd); \
    ze = sfma4((S), (WB)[14], ze); zf = sfma4((S), (WB)[15], zf); } while (0)
#define FMA16Y(S, WB) do { \
    y0 = sfma4((S), (WB)[0],  y0); y1 = sfma4((S), (WB)[1],  y1); \
    y2 = sfma4((S), (WB)[2],  y2); y3 = sfma4((S), (WB)[3],  y3); \
    y4 = sfma4((S), (WB)[4],  y4); y5 = sfma4((S), (WB)[5],  y5); \
    y6 = sfma4((S), (WB)[6],  y6); y7 = sfma4((S), (WB)[7],  y7); \
    y8 = sfma4((S), (WB)[8],  y8); y9 = sfma4((S), (WB)[9],  y9); \
    ya = sfma4((S), (WB)[10], ya); yb = sfma4((S), (WB)[11], yb); \
    yc = sfma4((S), (WB)[12], yc); yd = sfma4((S), (WB)[13], yd); \
    ye = sfma4((S), (WB)[14], ye); yf = sfma4((S), (WB)[15], yf); } while (0)

// ---------------- A[u][e][d] = sum_r gU[e][d][r] * (sum_dd ut[u][dd]*gV[e][dd][r]) ----------------
__global__ void k_prep(const float* __restrict__ gU, const float* __restrict__ gV,
                       const float* __restrict__ ut, float* __restrict__ A)
{
    int idx = blockIdx.x * 256 + threadIdx.x;
    if (idx >= NUSERS * NE) return;
    int u = idx / NE, e = idx - u * NE;

    const float4* up = (const float4*)(ut + (size_t)u * UDIM);
    float4 u0 = up[0], u1 = up[1], u2 = up[2], u3 = up[3];

    float4 va = make_float4(0.f, 0.f, 0.f, 0.f);
    float4 vb = make_float4(0.f, 0.f, 0.f, 0.f);
    const float4* gv4 = (const float4*)gV;
#define UVSTEP(UD, DD) do { \
        float4 g0 = gv4[(e * UDIM + (DD)) * 2 + 0]; \
        float4 g1 = gv4[(e * UDIM + (DD)) * 2 + 1]; \
        va = sfma4((UD), g0, va); vb = sfma4((UD), g1, vb); } while (0)
    UVSTEP(u0.x, 0);  UVSTEP(u0.y, 1);  UVSTEP(u0.z, 2);  UVSTEP(u0.w, 3);
    UVSTEP(u1.x, 4);  UVSTEP(u1.y, 5);  UVSTEP(u1.z, 6);  UVSTEP(u1.w, 7);
    UVSTEP(u2.x, 8);  UVSTEP(u2.y, 9);  UVSTEP(u2.z, 10); UVSTEP(u2.w, 11);
    UVSTEP(u3.x, 12); UVSTEP(u3.y, 13); UVSTEP(u3.z, 14); UVSTEP(u3.w, 15);
#undef UVSTEP

    const float4* gu4 = (const float4*)gU;
    float* Ao = A + ((size_t)u * NE + e) * EMB;
    for (int d = 0; d < EMB; ++d) {
        float4 q0 = gu4[(e * EMB + d) * 2 + 0];
        float4 q1 = gu4[(e * EMB + d) * 2 + 1];
        float a = 0.0f;
        a = fmaf(q0.x, va.x, a); a = fmaf(q0.y, va.y, a);
        a = fmaf(q0.z, va.z, a); a = fmaf(q0.w, va.w, a);
        a = fmaf(q1.x, vb.x, a); a = fmaf(q1.y, vb.y, a);
        a = fmaf(q1.z, vb.z, a); a = fmaf(q1.w, vb.w, a);
        Ao[d] = a;
    }
}

// ---------------- fused backbone + gate + top2 ----------------
// Register discipline: y(64) accumulates across kernel; fc1 runs in 16-output
// chunks (a0..a3) with x streamed in 16-float windows (#pragma unroll 1 blocks
// hoisting); each chunk is gelu'd then immediately folded into y (partial fc2).
// Peak live ~96 floats. d-order ascending everywhere = bit-identical numerics.
__global__ __launch_bounds__(256) void k_bbgate(
    const float* __restrict__ x, const int* __restrict__ uid,
    const float* __restrict__ w1, const float* __restrict__ b1,
    const float* __restrict__ w2, const float* __restrict__ b2,
    const float* __restrict__ gam, const float* __restrict__ bet,
    const float* __restrict__ A, const float* __restrict__ gb,
    float* __restrict__ h_out,
    int* __restrict__ top_e, float* __restrict__ top_w, int* __restrict__ hist)
{
    __shared__ __align__(16) float4 s_w1[IN_F * 16];   // 20 KB  [d][k4]
    __shared__ __align__(16) float4 s_w2[EMB * 16];    // 16 KB  [d][k4]
    __shared__ __align__(16) float4 s_b1[16], s_b2[16], s_ga[16], s_be[16];
    __shared__ float s_gb[NE];
    __shared__ int s_hist[NE];

    const int tid = threadIdx.x;
    {
        const float4* g1 = (const float4*)w1;
        for (int i = tid; i < IN_F * 16; i += 256) s_w1[i] = g1[i];
        const float4* g2 = (const float4*)w2;
        for (int i = tid; i < EMB * 16; i += 256) s_w2[i] = g2[i];
        if (tid < 16) {
            s_b1[tid] = ((const float4*)b1)[tid];
            s_b2[tid] = ((const float4*)b2)[tid];
            s_ga[tid] = ((const float4*)gam)[tid];
            s_be[tid] = ((const float4*)bet)[tid];
        }
        if (tid < NE) { s_gb[tid] = gb[tid]; s_hist[tid] = 0; }
    }
    __syncthreads();

    const int b = blockIdx.x * 256 + tid;
    const float4* xp = (const float4*)(x + (size_t)b * IN_F);

    // y = fc2 accumulator (bias-init), carried through all fc1 chunks
    float4 y0 = s_b2[0],  y1 = s_b2[1],  y2 = s_b2[2],  y3 = s_b2[3];
    float4 y4 = s_b2[4],  y5 = s_b2[5],  y6 = s_b2[6],  y7 = s_b2[7];
    float4 y8 = s_b2[8],  y9 = s_b2[9],  ya = s_b2[10], yb = s_b2[11];
    float4 yc = s_b2[12], yd = s_b2[13], ye = s_b2[14], yf = s_b2[15];

#define ACC4(S) do { \
    a0 = sfma4((S), wr[0], a0); a1 = sfma4((S), wr[1], a1); \
    a2 = sfma4((S), wr[2], a2); a3 = sfma4((S), wr[3], a3); wr += 16; } while (0)

#define BBKC(KC) do { \
    float4 a0 = s_b1[(KC)*4+0], a1 = s_b1[(KC)*4+1], a2 = s_b1[(KC)*4+2], a3 = s_b1[(KC)*4+3]; \
    _Pragma("unroll 1") \
    for (int t = 0; t < 5; ++t) { \
        float4 xA = xp[4*t+0], xB = xp[4*t+1], xC = xp[4*t+2], xD = xp[4*t+3]; \
        const float4* wr = s_w1 + (t * 16) * 16 + (KC) * 4; \
        ACC4(xA.x); ACC4(xA.y); ACC4(xA.z); ACC4(xA.w); \
        ACC4(xB.x); ACC4(xB.y); ACC4(xB.z); ACC4(xB.w); \
        ACC4(xC.x); ACC4(xC.y); ACC4(xC.z); ACC4(xC.w); \
        ACC4(xD.x); ACC4(xD.y); ACC4(xD.z); ACC4(xD.w); \
    } \
    a0 = gelu4(a0); a1 = gelu4(a1); a2 = gelu4(a2); a3 = gelu4(a3); \
    { const float4* w2r = s_w2 + ((KC) * 16) * 16; \
      FMA16Y(a0.x, w2r);        FMA16Y(a0.y, w2r + 16);  FMA16Y(a0.z, w2r + 32);  FMA16Y(a0.w, w2r + 48); \
      FMA16Y(a1.x, w2r + 64);   FMA16Y(a1.y, w2r + 80);  FMA16Y(a1.z, w2r + 96);  FMA16Y(a1.w, w2r + 112); \
      FMA16Y(a2.x, w2r + 128);  FMA16Y(a2.y, w2r + 144); FMA16Y(a2.z, w2r + 160); FMA16Y(a2.w, w2r + 176); \
      FMA16Y(a3.x, w2r + 192);  FMA16Y(a3.y, w2r + 208); FMA16Y(a3.z, w2r + 224); FMA16Y(a3.w, w2r + 240); } \
} while (0)

    BBKC(0); BBKC(1); BBKC(2); BBKC(3);
#undef BBKC
#undef ACC4

    // gelu on y
    y0 = gelu4(y0); y1 = gelu4(y1); y2 = gelu4(y2); y3 = gelu4(y3);
    y4 = gelu4(y4); y5 = gelu4(y5); y6 = gelu4(y6); y7 = gelu4(y7);
    y8 = gelu4(y8); y9 = gelu4(y9); ya = gelu4(ya); yb = gelu4(yb);
    yc = gelu4(yc); yd = gelu4(yd); ye = gelu4(ye); yf = gelu4(yf);

    // LayerNorm
    float4 sA = add4(add4(add4(y0, y1), add4(y2, y3)), add4(add4(y4, y5), add4(y6, y7)));
    float4 sB = add4(add4(add4(y8, y9), add4(ya, yb)), add4(add4(yc, yd), add4(ye, yf)));
    float4 sS = add4(sA, sB);
    float mu = (sS.x + sS.y + sS.z + sS.w) * (1.0f / 64.0f);
    float4 vv = make_float4(0.f, 0.f, 0.f, 0.f);
#define BBV(Z) do { float4 d4; d4.x = (Z).x - mu; d4.y = (Z).y - mu; d4.z = (Z).z - mu; d4.w = (Z).w - mu; \
                    vv = ffma4(d4, d4, vv); } while (0)
    BBV(y0); BBV(y1); BBV(y2); BBV(y3); BBV(y4); BBV(y5); BBV(y6); BBV(y7);
    BBV(y8); BBV(y9); BBV(ya); BBV(yb); BBV(yc); BBV(yd); BBV(ye); BBV(yf);
#undef BBV
    float var = (vv.x + vv.y + vv.z + vv.w) * (1.0f / 64.0f);
    float inv = 1.0f / sqrtf(var + 1e-5f);
    y0 = ln4(y0, mu, inv, s_ga[0],  s_be[0]);
    y1 = ln4(y1, mu, inv, s_ga[1],  s_be[1]);
    y2 = ln4(y2, mu, inv, s_ga[2],  s_be[2]);
    y3 = ln4(y3, mu, inv, s_ga[3],  s_be[3]);
    y4 = ln4(y4, mu, inv, s_ga[4],  s_be[4]);
    y5 = ln4(y5, mu, inv, s_ga[5],  s_be[5]);
    y6 = ln4(y6, mu, inv, s_ga[6],  s_be[6]);
    y7 = ln4(y7, mu, inv, s_ga[7],  s_be[7]);
    y8 = ln4(y8, mu, inv, s_ga[8],  s_be[8]);
    y9 = ln4(y9, mu, inv, s_ga[9],  s_be[9]);
    ya = ln4(ya, mu, inv, s_ga[10], s_be[10]);
    yb = ln4(yb, mu, inv, s_ga[11], s_be[11]);
    yc = ln4(yc, mu, inv, s_ga[12], s_be[12]);
    yd = ln4(yd, mu, inv, s_ga[13], s_be[13]);
    ye = ln4(ye, mu, inv, s_ga[14], s_be[14]);
    yf = ln4(yf, mu, inv, s_ga[15], s_be[15]);

    {
        float4* ho = (float4*)(h_out + (size_t)b * EMB);
        ho[0] = y0;  ho[1] = y1;  ho[2] = y2;  ho[3] = y3;
        ho[4] = y4;  ho[5] = y5;  ho[6] = y6;  ho[7] = y7;
        ho[8] = y8;  ho[9] = y9;  ho[10] = ya; ho[11] = yb;
        ho[12] = yc; ho[13] = yd; ho[14] = ye; ho[15] = yf;
    }

    // gate + running top-2 (lowest index wins ties)
    const int u = uid[b];
    const float4* Ap = (const float4*)(A + (size_t)u * NE * EMB);
    float m0 = -1e30f, m1 = -1e30f;
    int i0 = 0, i1 = 0;
#pragma unroll 1
    for (int e = 0; e < NE; ++e) {
        const float4* ap = Ap + e * 16;
        float4 ac = make_float4(0.f, 0.f, 0.f, 0.f);
        ac = ffma4(y0, ap[0],  ac); ac = ffma4(y1, ap[1],  ac);
        ac = ffma4(y2, ap[2],  ac); ac = ffma4(y3, ap[3],  ac);
        ac = ffma4(y4, ap[4],  ac); ac = ffma4(y5, ap[5],  ac);
        ac = ffma4(y6, ap[6],  ac); ac = ffma4(y7, ap[7],  ac);
        ac = ffma4(y8, ap[8],  ac); ac = ffma4(y9, ap[9],  ac);
        ac = ffma4(ya, ap[10], ac); ac = ffma4(yb, ap[11], ac);
        ac = ffma4(yc, ap[12], ac); ac = ffma4(yd, ap[13], ac);
        ac = ffma4(ye, ap[14], ac); ac = ffma4(yf, ap[15], ac);
        float ge = ((ac.x + ac.y) + (ac.z + ac.w)) + s_gb[e];
        if (ge > m0)      { m1 = m0; i1 = i0; m0 = ge; i0 = e; }
        else if (ge > m1) { m1 = ge; i1 = e; }
    }
    float t = expf(m1 - m0);
    float w0n = 1.0f / (1.0f + t);
    float w1n = t / (1.0f + t);

    top_e[2*b+0] = i0; top_w[2*b+0] = w0n;
    top_e[2*b+1] = i1; top_w[2*b+1] = w1n;
    atomicAdd(&s_hist[i0], 1);
    atomicAdd(&s_hist[i1], 1);
    __syncthreads();
    if (tid < NE) atomicAdd(&hist[tid], s_hist[tid]);
}

// ---------------- tiny exclusive scan ----------------
__global__ void k_scan(const int* __restrict__ hist, int* __restrict__ offs, int* __restrict__ cur)
{
    if (blockIdx.x == 0 && threadIdx.x == 0) {
        int acc = 0;
        for (int e = 0; e < NE; ++e) { offs[e] = acc; cur[e] = acc; acc += hist[e]; }
    }
}

// ---------------- block-aggregated scatter ----------------
__global__ __launch_bounds__(256) void k_scatter(
    const int* __restrict__ top_e, const float* __restrict__ top_w,
    int* __restrict__ cur, int* __restrict__ pair_b, float* __restrict__ pair_w)
{
    __shared__ int lh[NE];
    __shared__ int lbase[NE];
    const int tid = threadIdx.x;
    if (tid < NE) lh[tid] = 0;
    __syncthreads();

    const int b = blockIdx.x * 256 + tid;
    const int e0 = top_e[2*b+0];
    const int e1 = top_e[2*b+1];
    atomicAdd(&lh[e0], 1);
    atomicAdd(&lh[e1], 1);
    __syncthreads();
    if (tid < NE) {
        lbase[tid] = atomicAdd(&cur[tid], lh[tid]);
        lh[tid] = 0;
    }
    __syncthreads();
    int r0 = atomicAdd(&lh[e0], 1);
    int p0 = lbase[e0] + r0;
    pair_b[p0] = b; pair_w[p0] = top_w[2*b+0];
    int r1 = atomicAdd(&lh[e1], 1);
    int p1 = lbase[e1] + r1;
    pair_b[p1] = b; pair_w[p1] = top_w[2*b+1];
}

// ---------------- expert: z(64) in regs, h streamed in 16-float windows ----------------
#define EXP_BX 128
__global__ __launch_bounds__(256) void k_expert(
    const float* __restrict__ h,
    const int* __restrict__ pair_b, const float* __restrict__ pair_w,
    const int* __restrict__ hist, const int* __restrict__ offs,
    const float* __restrict__ ew1, const float* __restrict__ eb1,
    const float* __restrict__ eg, const float* __restrict__ ebeta,
    const float* __restrict__ ew2, const float* __restrict__ eb2,
    float* __restrict__ out)
{
    const int e = blockIdx.y;
    const int cnt = hist[e];
    if ((int)(blockIdx.x * 256) >= cnt) return;

    __shared__ __align__(16) float4 s_w1[EMB * 16];    // 16 KB [d][k4]
    __shared__ __align__(16) float4 s_w2[EMB * 3];     // 3 KB  [k][c4] padded 10->12
    __shared__ __align__(16) float4 s_b1[16], s_ga[16], s_be[16], s_b2[3];

    const int tid = threadIdx.x;
    {
        const float4* g1 = (const float4*)(ew1 + (size_t)e * EMB * EMB);
        for (int i = tid; i < EMB * 16; i += 256) s_w1[i] = g1[i];
        float* w2f = (float*)s_w2;
        for (int i = tid; i < EMB * 12; i += 256) {
            int k = i / 12, c = i - k * 12;
            w2f[i] = (c < NCLS) ? ew2[((size_t)e * EMB + k) * NCLS + c] : 0.0f;
        }
        if (tid < 16) {
            s_b1[tid] = ((const float4*)(eb1   + (size_t)e * EMB))[tid];
            s_ga[tid] = ((const float4*)(eg    + (size_t)e * EMB))[tid];
            s_be[tid] = ((const float4*)(ebeta + (size_t)e * EMB))[tid];
        }
        float* b2f = (float*)s_b2;
        if (tid < 12) b2f[tid] = (tid < NCLS) ? eb2[e * NCLS + tid] : 0.0f;
    }
    __syncthreads();

    const int base = offs[e];

    for (int lane = blockIdx.x * 256 + tid; lane < cnt; lane += EXP_BX * 256) {
        const int idx = base + lane;
        const int b = pair_b[idx];
        const float pw = pair_w[idx];

        const float4* hp = (const float4*)(h + (size_t)b * EMB);

        // fc1: z accumulates; h streamed in 4 windows of 4 float4 (unroll 1
        // keeps only one window live -> peak ~85 floats, no spill)
        float4 z0 = s_b1[0],  z1 = s_b1[1],  z2 = s_b1[2],  z3 = s_b1[3];
        float4 z4 = s_b1[4],  z5 = s_b1[5],  z6 = s_b1[6],  z7 = s_b1[7];
        float4 z8 = s_b1[8],  z9 = s_b1[9],  za = s_b1[10], zb = s_b1[11];
        float4 zc = s_b1[12], zd = s_b1[13], ze = s_b1[14], zf = s_b1[15];
#pragma unroll 1
        for (int t = 0; t < 4; ++t) {
            float4 hA = hp[4*t+0], hB = hp[4*t+1], hC = hp[4*t+2], hD = hp[4*t+3];
            const float4* wr = s_w1 + (t * 16) * 16;
            FMA16Z(hA.x, wr);       FMA16Z(hA.y, wr + 16);  FMA16Z(hA.z, wr + 32);  FMA16Z(hA.w, wr + 48);
            FMA16Z(hB.x, wr + 64);  FMA16Z(hB.y, wr + 80);  FMA16Z(hB.z, wr + 96);  FMA16Z(hB.w, wr + 112);
            FMA16Z(hC.x, wr + 128); FMA16Z(hC.y, wr + 144); FMA16Z(hC.z, wr + 160); FMA16Z(hC.w, wr + 176);
            FMA16Z(hD.x, wr + 192); FMA16Z(hD.y, wr + 208); FMA16Z(hD.z, wr + 224); FMA16Z(hD.w, wr + 240);
        }
        z0 = gelu4(z0); z1 = gelu4(z1); z2 = gelu4(z2); z3 = gelu4(z3);
        z4 = gelu4(z4); z5 = gelu4(z5); z6 = gelu4(z6); z7 = gelu4(z7);
        z8 = gelu4(z8); z9 = gelu4(z9); za = gelu4(za); zb = gelu4(zb);
        zc = gelu4(zc); zd = gelu4(zd); ze = gelu4(ze); zf = gelu4(zf);

        // LayerNorm (static)
        float4 sA = add4(add4(add4(z0, z1), add4(z2, z3)), add4(add4(z4, z5), add4(z6, z7)));
        float4 sB = add4(add4(add4(z8, z9), add4(za, zb)), add4(add4(zc, zd), add4(ze, zf)));
        float4 sS = add4(sA, sB);
        float mu = (sS.x + sS.y + sS.z + sS.w) * (1.0f / 64.0f);
        float4 vv = make_float4(0.f, 0.f, 0.f, 0.f);
#define EXV(Z) do { float4 d4; d4.x = (Z).x - mu; d4.y = (Z).y - mu; d4.z = (Z).z - mu; d4.w = (Z).w - mu; \
                    vv = ffma4(d4, d4, vv); } while (0)
        EXV(z0); EXV(z1); EXV(z2); EXV(z3); EXV(z4); EXV(z5); EXV(z6); EXV(z7);
        EXV(z8); EXV(z9); EXV(za); EXV(zb); EXV(zc); EXV(zd); EXV(ze); EXV(zf);
#undef EXV
        float var = (vv.x + vv.y + vv.z + vv.w) * (1.0f / 64.0f);
        float inv = 1.0f / sqrtf(var + 1e-5f);
        z0 = ln4(z0, mu, inv, s_ga[0],  s_be[0]);
        z1 = ln4(z1, mu, inv, s_ga[1],  s_be[1]);
        z2 = ln4(z2, mu, inv, s_ga[2],  s_be[2]);
        z3 = ln4(z3, mu, inv, s_ga[3],  s_be[3]);
        z4 = ln4(z4, mu, inv, s_ga[4],  s_be[4]);
        z5 = ln4(z5, mu, inv, s_ga[5],  s_be[5]);
        z6 = ln4(z6, mu, inv, s_ga[6],  s_be[6]);
        z7 = ln4(z7, mu, inv, s_ga[7],  s_be[7]);
        z8 = ln4(z8, mu, inv, s_ga[8],  s_be[8]);
        z9 = ln4(z9, mu, inv, s_ga[9],  s_be[9]);
        za = ln4(za, mu, inv, s_ga[10], s_be[10]);
        zb = ln4(zb, mu, inv, s_ga[11], s_be[11]);
        zc = ln4(zc, mu, inv, s_ga[12], s_be[12]);
        zd = ln4(zd, mu, inv, s_ga[13], s_be[13]);
        ze = ln4(ze, mu, inv, s_ga[14], s_be[14]);
        zf = ln4(zf, mu, inv, s_ga[15], s_be[15]);

        // fc2 (64 -> 12 padded), fully static
        float4 a0 = s_b2[0], a1 = s_b2[1], a2 = s_b2[2];
#define EXF2(ZQ, DB) do { \
        const float4* wr = s_w2 + (DB) * 3; \
        a0 = sfma4((ZQ).x, wr[0],  a0); a1 = sfma4((ZQ).x, wr[1],  a1); a2 = sfma4((ZQ).x, wr[2],  a2); \
        a0 = sfma4((ZQ).y, wr[3],  a0); a1 = sfma4((ZQ).y, wr[4],  a1); a2 = sfma4((ZQ).y, wr[5],  a2); \
        a0 = sfma4((ZQ).z, wr[6],  a0); a1 = sfma4((ZQ).z, wr[7],  a1); a2 = sfma4((ZQ).z, wr[8],  a2); \
        a0 = sfma4((ZQ).w, wr[9],  a0); a1 = sfma4((ZQ).w, wr[10], a1); a2 = sfma4((ZQ).w, wr[11], a2); \
} while (0)
        EXF2(z0, 0);  EXF2(z1, 4);  EXF2(z2, 8);  EXF2(z3, 12);
        EXF2(z4, 16); EXF2(z5, 20); EXF2(z6, 24); EXF2(z7, 28);
        EXF2(z8, 32); EXF2(z9, 36); EXF2(za, 40); EXF2(zb, 44);
        EXF2(zc, 48); EXF2(zd, 52); EXF2(ze, 56); EXF2(zf, 60);
#undef EXF2

        float* ob = out + (size_t)b * NCLS;
        atomicAdd(ob + 0, pw * a0.x);
        atomicAdd(ob + 1, pw * a0.y);
        atomicAdd(ob + 2, pw * a0.z);
        atomicAdd(ob + 3, pw * a0.w);
        atomicAdd(ob + 4, pw * a1.x);
        atomicAdd(ob + 5, pw * a1.y);
        atomicAdd(ob + 6, pw * a1.z);
        atomicAdd(ob + 7, pw * a1.w);
        atomicAdd(ob + 8, pw * a2.x);
        atomicAdd(ob + 9, pw * a2.y);
    }
}

extern "C" void kernel_launch(void* const* d_in, const int* in_sizes, int n_in,
                              void* d_out, int out_size, void* d_ws, size_t ws_size,
                              hipStream_t stream)
{
    (void)in_sizes; (void)n_in; (void)out_size; (void)ws_size;

    const float* x     = (const float*)d_in[0];
    const int*   uid   = (const int*)  d_in[1];
    const float* bb_w1 = (const float*)d_in[2];
    const float* bb_b1 = (const float*)d_in[3];
    const float* bb_w2 = (const float*)d_in[4];
    const float* bb_b2 = (const float*)d_in[5];
    const float* bb_g  = (const float*)d_in[6];
    const float* bb_be = (const float*)d_in[7];
    const float* gU    = (const float*)d_in[8];
    const float* gV    = (const float*)d_in[9];
    const float* gb    = (const float*)d_in[10];
    const float* e_w1  = (const float*)d_in[11];
    const float* e_b1  = (const float*)d_in[12];
    const float* e_g   = (const float*)d_in[13];
    const float* e_be  = (const float*)d_in[14];
    const float* e_w2  = (const float*)d_in[15];
    const float* e_b2  = (const float*)d_in[16];
    const float* ut    = (const float*)d_in[17];

    float* out = (float*)d_out;
    char*  ws  = (char*)d_ws;

    float* h      = (float*)(ws + OFF_H);
    float* A      = (float*)(ws + OFF_A);
    int*   top_e  = (int*)  (ws + OFF_TOPE);
    float* top_w  = (float*)(ws + OFF_TOPW);
    int*   pair_b = (int*)  (ws + OFF_PAIRB);
    float* pair_w = (float*)(ws + OFF_PAIRW);
    int*   hist   = (int*)  (ws + OFF_HIST);
    int*   offs   = (int*)  (ws + OFF_OFFS);
    int*   cur    = (int*)  (ws + OFF_CUR);

    hipMemsetAsync(out, 0, (size_t)BATCH * NCLS * sizeof(float), stream);
    hipMemsetAsync(hist, 0, NE * sizeof(int), stream);

    k_prep<<<(NUSERS * NE + 255) / 256, 256, 0, stream>>>(gU, gV, ut, A);
    k_bbgate<<<BATCH / 256, 256, 0, stream>>>(x, uid, bb_w1, bb_b1, bb_w2, bb_b2,
                                              bb_g, bb_be, A, gb, h, top_e, top_w, hist);
    k_scan<<<1, 64, 0, stream>>>(hist, offs, cur);
    k_scatter<<<BATCH / 256, 256, 0, stream>>>(top_e, top_w, cur, pair_b, pair_w);
    dim3 eg(EXP_BX, NE);
    k_expert<<<eg, 256, 0, stream>>>(h, pair_b, pair_w, hist, offs,
                                     e_w1, e_b1, e_g, e_be, e_w2, e_b2, out);
}

// Round 8
// 520.242 us; speedup vs baseline: 26.4154x; 6.1177x over previous
//
#include <hip/hip_runtime.h>
#include <math.h>

#define BATCH   131072
#define IN_F    80
#define EMB     64
#define NE      16
#define RANK    8
#define UDIM    16
#define NCLS    10
#define NUSERS  1000

// ---- workspace layout (bytes) ----
#define OFF_H      0ull                 // BATCH*64 f32 (h1, then h in-place)
#define OFF_A      33554432ull          // NUSERS*16*64 f32
#define OFF_TOPE   37650432ull
#define OFF_TOPW   38699008ull
#define OFF_PAIRB  39747584ull
#define OFF_PAIRW  40796160ull
#define OFF_HIST   41844736ull
#define OFF_OFFS   41845760ull
#define OFF_CUR    41846784ull

__device__ __forceinline__ float gelu_f(float v) {
    return 0.5f * v * (1.0f + erff(v * 0.70710678118654752440f));
}
__device__ __forceinline__ float4 gelu4(float4 v) {
    v.x = gelu_f(v.x); v.y = gelu_f(v.y); v.z = gelu_f(v.z); v.w = gelu_f(v.w);
    return v;
}
__device__ __forceinline__ float4 sfma4(float s, float4 w, float4 a) {
    a.x = fmaf(s, w.x, a.x); a.y = fmaf(s, w.y, a.y);
    a.z = fmaf(s, w.z, a.z); a.w = fmaf(s, w.w, a.w);
    return a;
}
__device__ __forceinline__ float4 ffma4(float4 v, float4 w, float4 a) {
    a.x = fmaf(v.x, w.x, a.x); a.y = fmaf(v.y, w.y, a.y);
    a.z = fmaf(v.z, w.z, a.z); a.w = fmaf(v.w, w.w, a.w);
    return a;
}
__device__ __forceinline__ float4 add4(float4 a, float4 b) {
    a.x += b.x; a.y += b.y; a.z += b.z; a.w += b.w; return a;
}
__device__ __forceinline__ float4 ln4(float4 z, float mu, float inv, float4 g, float4 bb) {
    float4 r;
    r.x = fmaf((z.x - mu) * inv, g.x, bb.x);
    r.y = fmaf((z.y - mu) * inv, g.y, bb.y);
    r.z = fmaf((z.z - mu) * inv, g.z, bb.z);
    r.w = fmaf((z.w - mu) * inv, g.w, bb.w);
    return r;
}

#define FMA16Z(S, WB) do { \
    z0 = sfma4((S), (WB)[0],  z0); z1 = sfma4((S), (WB)[1],  z1); \
    z2 = sfma4((S), (WB)[2],  z2); z3 = sfma4((S), (WB)[3],  z3); \
    z4 = sfma4((S), (WB)[4],  z4); z5 = sfma4((S), (WB)[5],  z5); \
    z6 = sfma4((S), (WB)[6],  z6); z7 = sfma4((S), (WB)[7],  z7); \
    z8 = sfma4((S), (WB)[8],  z8); z9 = sfma4((S), (WB)[9],  z9); \
    za = sfma4((S), (WB)[10], za); zb = sfma4((S), (WB)[11], zb); \
    zc = sfma4((S), (WB)[12], zc); zd = sfma4((S), (WB)[13], zd); \
    ze = sfma4((S), (WB)[14], ze); zf = sfma4((S), (WB)[15], zf); } while (0)

// ---------------- A[u][e][d] precompute ----------------
__global__ void k_prep(const float* __restrict__ gU, const float* __restrict__ gV,
                       const float* __restrict__ ut, float* __restrict__ A)
{
    int idx = blockIdx.x * 256 + threadIdx.x;
    if (idx >= NUSERS * NE) return;
    int u = idx / NE, e = idx - u * NE;

    const float4* up = (const float4*)(ut + (size_t)u * UDIM);
    float4 u0 = up[0], u1 = up[1], u2 = up[2], u3 = up[3];

    float4 va = make_float4(0.f, 0.f, 0.f, 0.f);
    float4 vb = make_float4(0.f, 0.f, 0.f, 0.f);
    const float4* gv4 = (const float4*)gV;
#define UVSTEP(UD, DD) do { \
        float4 g0 = gv4[(e * UDIM + (DD)) * 2 + 0]; \
        float4 g1 = gv4[(e * UDIM + (DD)) * 2 + 1]; \
        va = sfma4((UD), g0, va); vb = sfma4((UD), g1, vb); } while (0)
    UVSTEP(u0.x, 0);  UVSTEP(u0.y, 1);  UVSTEP(u0.z, 2);  UVSTEP(u0.w, 3);
    UVSTEP(u1.x, 4);  UVSTEP(u1.y, 5);  UVSTEP(u1.z, 6);  UVSTEP(u1.w, 7);
    UVSTEP(u2.x, 8);  UVSTEP(u2.y, 9);  UVSTEP(u2.z, 10); UVSTEP(u2.w, 11);
    UVSTEP(u3.x, 12); UVSTEP(u3.y, 13); UVSTEP(u3.z, 14); UVSTEP(u3.w, 15);
#undef UVSTEP

    const float4* gu4 = (const float4*)gU;
    float* Ao = A + ((size_t)u * NE + e) * EMB;
    for (int d = 0; d < EMB; ++d) {
        float4 q0 = gu4[(e * EMB + d) * 2 + 0];
        float4 q1 = gu4[(e * EMB + d) * 2 + 1];
        float a = 0.0f;
        a = fmaf(q0.x, va.x, a); a = fmaf(q0.y, va.y, a);
        a = fmaf(q0.z, va.z, a); a = fmaf(q0.w, va.w, a);
        a = fmaf(q1.x, vb.x, a); a = fmaf(q1.y, vb.y, a);
        a = fmaf(q1.z, vb.z, a); a = fmaf(q1.w, vb.w, a);
        Ao[d] = a;
    }
}

// ---------------- fc1: x streamed once, z(64) acc, gelu -> h1 ----------------
// Proven no-spill profile (k_expert R7): one 64-wide accumulator + 16-float window.
__global__ __launch_bounds__(256) void k_fc1(
    const float* __restrict__ x,
    const float* __restrict__ w1, const float* __restrict__ b1,
    float* __restrict__ h1_out)
{
    __shared__ __align__(16) float4 s_w1[IN_F * 16];   // 20 KB [d][k4]
    __shared__ __align__(16) float4 s_b1[16];

    const int tid = threadIdx.x;
    {
        const float4* g1 = (const float4*)w1;
        for (int i = tid; i < IN_F * 16; i += 256) s_w1[i] = g1[i];
        if (tid < 16) s_b1[tid] = ((const float4*)b1)[tid];
    }
    __syncthreads();

    const int b = blockIdx.x * 256 + tid;
    const float4* xp = (const float4*)(x + (size_t)b * IN_F);

    float4 z0 = s_b1[0],  z1 = s_b1[1],  z2 = s_b1[2],  z3 = s_b1[3];
    float4 z4 = s_b1[4],  z5 = s_b1[5],  z6 = s_b1[6],  z7 = s_b1[7];
    float4 z8 = s_b1[8],  z9 = s_b1[9],  za = s_b1[10], zb = s_b1[11];
    float4 zc = s_b1[12], zd = s_b1[13], ze = s_b1[14], zf = s_b1[15];

#pragma unroll 1
    for (int t = 0; t < 5; ++t) {
        float4 xA = xp[4*t+0], xB = xp[4*t+1], xC = xp[4*t+2], xD = xp[4*t+3];
        const float4* wr = s_w1 + (t * 16) * 16;
        FMA16Z(xA.x, wr);       FMA16Z(xA.y, wr + 16);  FMA16Z(xA.z, wr + 32);  FMA16Z(xA.w, wr + 48);
        FMA16Z(xB.x, wr + 64);  FMA16Z(xB.y, wr + 80);  FMA16Z(xB.z, wr + 96);  FMA16Z(xB.w, wr + 112);
        FMA16Z(xC.x, wr + 128); FMA16Z(xC.y, wr + 144); FMA16Z(xC.z, wr + 160); FMA16Z(xC.w, wr + 176);
        FMA16Z(xD.x, wr + 192); FMA16Z(xD.y, wr + 208); FMA16Z(xD.z, wr + 224); FMA16Z(xD.w, wr + 240);
    }
    z0 = gelu4(z0); z1 = gelu4(z1); z2 = gelu4(z2); z3 = gelu4(z3);
    z4 = gelu4(z4); z5 = gelu4(z5); z6 = gelu4(z6); z7 = gelu4(z7);
    z8 = gelu4(z8); z9 = gelu4(z9); za = gelu4(za); zb = gelu4(zb);
    zc = gelu4(zc); zd = gelu4(zd); ze = gelu4(ze); zf = gelu4(zf);

    float4* ho = (float4*)(h1_out + (size_t)b * EMB);
    ho[0] = z0;  ho[1] = z1;  ho[2] = z2;  ho[3] = z3;
    ho[4] = z4;  ho[5] = z5;  ho[6] = z6;  ho[7] = z7;
    ho[8] = z8;  ho[9] = z9;  ho[10] = za; ho[11] = zb;
    ho[12] = zc; ho[13] = zd; ho[14] = ze; ho[15] = zf;
}

// ---------------- fc2 + gelu + LN + gate + top2; h1 -> h in place ----------------
__global__ __launch_bounds__(256) void k_fc2gate(
    float* h,                                 // in: h1, out: h (same buffer, own row)
    const int* __restrict__ uid,
    const float* __restrict__ w2, const float* __restrict__ b2,
    const float* __restrict__ gam, const float* __restrict__ bet,
    const float* __restrict__ A, const float* __restrict__ gb,
    int* __restrict__ top_e, float* __restrict__ top_w, int* __restrict__ hist)
{
    __shared__ __align__(16) float4 s_w2[EMB * 16];    // 16 KB [d][k4]
    __shared__ __align__(16) float4 s_b2[16], s_ga[16], s_be[16];
    __shared__ float s_gb[NE];
    __shared__ int s_hist[NE];

    const int tid = threadIdx.x;
    {
        const float4* g2 = (const float4*)w2;
        for (int i = tid; i < EMB * 16; i += 256) s_w2[i] = g2[i];
        if (tid < 16) {
            s_b2[tid] = ((const float4*)b2)[tid];
            s_ga[tid] = ((const float4*)gam)[tid];
            s_be[tid] = ((const float4*)bet)[tid];
        }
        if (tid < NE) { s_gb[tid] = gb[tid]; s_hist[tid] = 0; }
    }
    __syncthreads();

    const int b = blockIdx.x * 256 + tid;
    float4* hp = (float4*)(h + (size_t)b * EMB);

    // fc2: y(64) acc, h1 streamed in windows (single pass, no CSE trap)
    float4 z0 = s_b2[0],  z1 = s_b2[1],  z2 = s_b2[2],  z3 = s_b2[3];
    float4 z4 = s_b2[4],  z5 = s_b2[5],  z6 = s_b2[6],  z7 = s_b2[7];
    float4 z8 = s_b2[8],  z9 = s_b2[9],  za = s_b2[10], zb = s_b2[11];
    float4 zc = s_b2[12], zd = s_b2[13], ze = s_b2[14], zf = s_b2[15];
#pragma unroll 1
    for (int t = 0; t < 4; ++t) {
        float4 hA = hp[4*t+0], hB = hp[4*t+1], hC = hp[4*t+2], hD = hp[4*t+3];
        const float4* wr = s_w2 + (t * 16) * 16;
        FMA16Z(hA.x, wr);       FMA16Z(hA.y, wr + 16);  FMA16Z(hA.z, wr + 32);  FMA16Z(hA.w, wr + 48);
        FMA16Z(hB.x, wr + 64);  FMA16Z(hB.y, wr + 80);  FMA16Z(hB.z, wr + 96);  FMA16Z(hB.w, wr + 112);
        FMA16Z(hC.x, wr + 128); FMA16Z(hC.y, wr + 144); FMA16Z(hC.z, wr + 160); FMA16Z(hC.w, wr + 176);
        FMA16Z(hD.x, wr + 192); FMA16Z(hD.y, wr + 208); FMA16Z(hD.z, wr + 224); FMA16Z(hD.w, wr + 240);
    }
    z0 = gelu4(z0); z1 = gelu4(z1); z2 = gelu4(z2); z3 = gelu4(z3);
    z4 = gelu4(z4); z5 = gelu4(z5); z6 = gelu4(z6); z7 = gelu4(z7);
    z8 = gelu4(z8); z9 = gelu4(z9); za = gelu4(za); zb = gelu4(zb);
    zc = gelu4(zc); zd = gelu4(zd); ze = gelu4(ze); zf = gelu4(zf);

    // LayerNorm
    float4 sA = add4(add4(add4(z0, z1), add4(z2, z3)), add4(add4(z4, z5), add4(z6, z7)));
    float4 sB = add4(add4(add4(z8, z9), add4(za, zb)), add4(add4(zc, zd), add4(ze, zf)));
    float4 sS = add4(sA, sB);
    float mu = (sS.x + sS.y + sS.z + sS.w) * (1.0f / 64.0f);
    float4 vv = make_float4(0.f, 0.f, 0.f, 0.f);
#define BBV(Z) do { float4 d4; d4.x = (Z).x - mu; d4.y = (Z).y - mu; d4.z = (Z).z - mu; d4.w = (Z).w - mu; \
                    vv = ffma4(d4, d4, vv); } while (0)
    BBV(z0); BBV(z1); BBV(z2); BBV(z3); BBV(z4); BBV(z5); BBV(z6); BBV(z7);
    BBV(z8); BBV(z9); BBV(za); BBV(zb); BBV(zc); BBV(zd); BBV(ze); BBV(zf);
#undef BBV
    float var = (vv.x + vv.y + vv.z + vv.w) * (1.0f / 64.0f);
    float inv = 1.0f / sqrtf(var + 1e-5f);
    z0 = ln4(z0, mu, inv, s_ga[0],  s_be[0]);
    z1 = ln4(z1, mu, inv, s_ga[1],  s_be[1]);
    z2 = ln4(z2, mu, inv, s_ga[2],  s_be[2]);
    z3 = ln4(z3, mu, inv, s_ga[3],  s_be[3]);
    z4 = ln4(z4, mu, inv, s_ga[4],  s_be[4]);
    z5 = ln4(z5, mu, inv, s_ga[5],  s_be[5]);
    z6 = ln4(z6, mu, inv, s_ga[6],  s_be[6]);
    z7 = ln4(z7, mu, inv, s_ga[7],  s_be[7]);
    z8 = ln4(z8, mu, inv, s_ga[8],  s_be[8]);
    z9 = ln4(z9, mu, inv, s_ga[9],  s_be[9]);
    za = ln4(za, mu, inv, s_ga[10], s_be[10]);
    zb = ln4(zb, mu, inv, s_ga[11], s_be[11]);
    zc = ln4(zc, mu, inv, s_ga[12], s_be[12]);
    zd = ln4(zd, mu, inv, s_ga[13], s_be[13]);
    ze = ln4(ze, mu, inv, s_ga[14], s_be[14]);
    zf = ln4(zf, mu, inv, s_ga[15], s_be[15]);

    // overwrite own row with final h
    hp[0] = z0;  hp[1] = z1;  hp[2] = z2;  hp[3] = z3;
    hp[4] = z4;  hp[5] = z5;  hp[6] = z6;  hp[7] = z7;
    hp[8] = z8;  hp[9] = z9;  hp[10] = za; hp[11] = zb;
    hp[12] = zc; hp[13] = zd; hp[14] = ze; hp[15] = zf;

    // gate + running top-2 (lowest index wins ties)
    const int u = uid[b];
    const float4* Ap = (const float4*)(A + (size_t)u * NE * EMB);
    float m0 = -1e30f, m1 = -1e30f;
    int i0 = 0, i1 = 0;
#pragma unroll 1
    for (int e = 0; e < NE; ++e) {
        const float4* ap = Ap + e * 16;
        float4 ac = make_float4(0.f, 0.f, 0.f, 0.f);
        ac = ffma4(z0, ap[0],  ac); ac = ffma4(z1, ap[1],  ac);
        ac = ffma4(z2, ap[2],  ac); ac = ffma4(z3, ap[3],  ac);
        ac = ffma4(z4, ap[4],  ac); ac = ffma4(z5, ap[5],  ac);
        ac = ffma4(z6, ap[6],  ac); ac = ffma4(z7, ap[7],  ac);
        ac = ffma4(z8, ap[8],  ac); ac = ffma4(z9, ap[9],  ac);
        ac = ffma4(za, ap[10], ac); ac = ffma4(zb, ap[11], ac);
        ac = ffma4(zc, ap[12], ac); ac = ffma4(zd, ap[13], ac);
        ac = ffma4(ze, ap[14], ac); ac = ffma4(zf, ap[15], ac);
        float ge = ((ac.x + ac.y) + (ac.z + ac.w)) + s_gb[e];
        if (ge > m0)      { m1 = m0; i1 = i0; m0 = ge; i0 = e; }
        else if (ge > m1) { m1 = ge; i1 = e; }
    }
    float t = expf(m1 - m0);
    float w0n = 1.0f / (1.0f + t);
    float w1n = t / (1.0f + t);

    top_e[2*b+0] = i0; top_w[2*b+0] = w0n;
    top_e[2*b+1] = i1; top_w[2*b+1] = w1n;
    atomicAdd(&s_hist[i0], 1);
    atomicAdd(&s_hist[i1], 1);
    __syncthreads();
    if (tid < NE) atomicAdd(&hist[tid], s_hist[tid]);
}

// ---------------- tiny exclusive scan ----------------
__global__ void k_scan(const int* __restrict__ hist, int* __restrict__ offs, int* __restrict__ cur)
{
    if (blockIdx.x == 0 && threadIdx.x == 0) {
        int acc = 0;
        for (int e = 0; e < NE; ++e) { offs[e] = acc; cur[e] = acc; acc += hist[e]; }
    }
}

// ---------------- block-aggregated scatter ----------------
__global__ __launch_bounds__(256) void k_scatter(
    const int* __restrict__ top_e, const float* __restrict__ top_w,
    int* __restrict__ cur, int* __restrict__ pair_b, float* __restrict__ pair_w)
{
    __shared__ int lh[NE];
    __shared__ int lbase[NE];
    const int tid = threadIdx.x;
    if (tid < NE) lh[tid] = 0;
    __syncthreads();

    const int b = blockIdx.x * 256 + tid;
    const int e0 = top_e[2*b+0];
    const int e1 = top_e[2*b+1];
    atomicAdd(&lh[e0], 1);
    atomicAdd(&lh[e1], 1);
    __syncthreads();
    if (tid < NE) {
        lbase[tid] = atomicAdd(&cur[tid], lh[tid]);
        lh[tid] = 0;
    }
    __syncthreads();
    int r0 = atomicAdd(&lh[e0], 1);
    int p0 = lbase[e0] + r0;
    pair_b[p0] = b; pair_w[p0] = top_w[2*b+0];
    int r1 = atomicAdd(&lh[e1], 1);
    int p1 = lbase[e1] + r1;
    pair_b[p1] = b; pair_w[p1] = top_w[2*b+1];
}

// ---------------- expert: z(64) in regs, h streamed in 16-float windows (R7, validated) ----------------
#define EXP_BX 128
__global__ __launch_bounds__(256) void k_expert(
    const float* __restrict__ h,
    const int* __restrict__ pair_b, const float* __restrict__ pair_w,
    const int* __restrict__ hist, const int* __restrict__ offs,
    const float* __restrict__ ew1, const float* __restrict__ eb1,
    const float* __restrict__ eg, const float* __restrict__ ebeta,
    const float* __restrict__ ew2, const float* __restrict__ eb2,
    float* __restrict__ out)
{
    const int e = blockIdx.y;
    const int cnt = hist[e];
    if ((int)(blockIdx.x * 256) >= cnt) return;

    __shared__ __align__(16) float4 s_w1[EMB * 16];    // 16 KB [d][k4]
    __shared__ __align__(16) float4 s_w2[EMB * 3];     // 3 KB  [k][c4] padded 10->12
    __shared__ __align__(16) float4 s_b1[16], s_ga[16], s_be[16], s_b2[3];

    const int tid = threadIdx.x;
    {
        const float4* g1 = (const float4*)(ew1 + (size_t)e * EMB * EMB);
        for (int i = tid; i < EMB * 16; i += 256) s_w1[i] = g1[i];
        float* w2f = (float*)s_w2;
        for (int i = tid; i < EMB * 12; i += 256) {
            int k = i / 12, c = i - k * 12;
            w2f[i] = (c < NCLS) ? ew2[((size_t)e * EMB + k) * NCLS + c] : 0.0f;
        }
        if (tid < 16) {
            s_b1[tid] = ((const float4*)(eb1   + (size_t)e * EMB))[tid];
            s_ga[tid] = ((const float4*)(eg    + (size_t)e * EMB))[tid];
            s_be[tid] = ((const float4*)(ebeta + (size_t)e * EMB))[tid];
        }
        float* b2f = (float*)s_b2;
        if (tid < 12) b2f[tid] = (tid < NCLS) ? eb2[e * NCLS + tid] : 0.0f;
    }
    __syncthreads();

    const int base = offs[e];

    for (int lane = blockIdx.x * 256 + tid; lane < cnt; lane += EXP_BX * 256) {
        const int idx = base + lane;
        const int b = pair_b[idx];
        const float pw = pair_w[idx];

        const float4* hp = (const float4*)(h + (size_t)b * EMB);

        float4 z0 = s_b1[0],  z1 = s_b1[1],  z2 = s_b1[2],  z3 = s_b1[3];
        float4 z4 = s_b1[4],  z5 = s_b1[5],  z6 = s_b1[6],  z7 = s_b1[7];
        float4 z8 = s_b1[8],  z9 = s_b1[9],  za = s_b1[10], zb = s_b1[11];
        float4 zc = s_b1[12], zd = s_b1[13], ze = s_b1[14], zf = s_b1[15];
#pragma unroll 1
        for (int t = 0; t < 4; ++t) {
            float4 hA = hp[4*t+0], hB = hp[4*t+1], hC = hp[4*t+2], hD = hp[4*t+3];
            const float4* wr = s_w1 + (t * 16) * 16;
            FMA16Z(hA.x, wr);       FMA16Z(hA.y, wr + 16);  FMA16Z(hA.z, wr + 32);  FMA16Z(hA.w, wr + 48);
            FMA16Z(hB.x, wr + 64);  FMA16Z(hB.y, wr + 80);  FMA16Z(hB.z, wr + 96);  FMA16Z(hB.w, wr + 112);
            FMA16Z(hC.x, wr + 128); FMA16Z(hC.y, wr + 144); FMA16Z(hC.z, wr + 160); FMA16Z(hC.w, wr + 176);
            FMA16Z(hD.x, wr + 192); FMA16Z(hD.y, wr + 208); FMA16Z(hD.z, wr + 224); FMA16Z(hD.w, wr + 240);
        }
        z0 = gelu4(z0); z1 = gelu4(z1); z2 = gelu4(z2); z3 = gelu4(z3);
        z4 = gelu4(z4); z5 = gelu4(z5); z6 = gelu4(z6); z7 = gelu4(z7);
        z8 = gelu4(z8); z9 = gelu4(z9); za = gelu4(za); zb = gelu4(zb);
        zc = gelu4(zc); zd = gelu4(zd); ze = gelu4(ze); zf = gelu4(zf);

        float4 sA = add4(add4(add4(z0, z1), add4(z2, z3)), add4(add4(z4, z5), add4(z6, z7)));
        float4 sB = add4(add4(add4(z8, z9), add4(za, zb)), add4(add4(zc, zd), add4(ze, zf)));
        float4 sS = add4(sA, sB);
        float mu = (sS.x + sS.y + sS.z + sS.w) * (1.0f / 64.0f);
        float4 vv = make_float4(0.f, 0.f, 0.f, 0.f);
#define EXV(Z) do { float4 d4; d4.x = (Z).x - mu; d4.y = (Z).y - mu; d4.z = (Z).z - mu; d4.w = (Z).w - mu; \
                    vv = ffma4(d4, d4, vv); } while (0)
        EXV(z0); EXV(z1); EXV(z2); EXV(z3); EXV(z4); EXV(z5); EXV(z6); EXV(z7);
        EXV(z8); EXV(z9); EXV(za); EXV(zb); EXV(zc); EXV(zd); EXV(ze); EXV(zf);
#undef EXV
        float var = (vv.x + vv.y + vv.z + vv.w) * (1.0f / 64.0f);
        float inv = 1.0f / sqrtf(var + 1e-5f);
        z0 = ln4(z0, mu, inv, s_ga[0],  s_be[0]);
        z1 = ln4(z1, mu, inv, s_ga[1],  s_be[1]);
        z2 = ln4(z2, mu, inv, s_ga[2],  s_be[2]);
        z3 = ln4(z3, mu, inv, s_ga[3],  s_be[3]);
        z4 = ln4(z4, mu, inv, s_ga[4],  s_be[4]);
        z5 = ln4(z5, mu, inv, s_ga[5],  s_be[5]);
        z6 = ln4(z6, mu, inv, s_ga[6],  s_be[6]);
        z7 = ln4(z7, mu, inv, s_ga[7],  s_be[7]);
        z8 = ln4(z8, mu, inv, s_ga[8],  s_be[8]);
        z9 = ln4(z9, mu, inv, s_ga[9],  s_be[9]);
        za = ln4(za, mu, inv, s_ga[10], s_be[10]);
        zb = ln4(zb, mu, inv, s_ga[11], s_be[11]);
        zc = ln4(zc, mu, inv, s_ga[12], s_be[12]);
        zd = ln4(zd, mu, inv, s_ga[13], s_be[13]);
        ze = ln4(ze, mu, inv, s_ga[14], s_be[14]);
        zf = ln4(zf, mu, inv, s_ga[15], s_be[15]);

        float4 a0 = s_b2[0], a1 = s_b2[1], a2 = s_b2[2];
#define EXF2(ZQ, DB) do { \
        const float4* wr = s_w2 + (DB) * 3; \
        a0 = sfma4((ZQ).x, wr[0],  a0); a1 = sfma4((ZQ).x, wr[1],  a1); a2 = sfma4((ZQ).x, wr[2],  a2); \
        a0 = sfma4((ZQ).y, wr[3],  a0); a1 = sfma4((ZQ).y, wr[4],  a1); a2 = sfma4((ZQ).y, wr[5],  a2); \
        a0 = sfma4((ZQ).z, wr[6],  a0); a1 = sfma4((ZQ).z, wr[7],  a1); a2 = sfma4((ZQ).z, wr[8],  a2); \
        a0 = sfma4((ZQ).w, wr[9],  a0); a1 = sfma4((ZQ).w, wr[10], a1); a2 = sfma4((ZQ).w, wr[11], a2); \
} while (0)
        EXF2(z0, 0);  EXF2(z1, 4);  EXF2(z2, 8);  EXF2(z3, 12);
        EXF2(z4, 16); EXF2(z5, 20); EXF2(z6, 24); EXF2(z7, 28);
        EXF2(z8, 32); EXF2(z9, 36); EXF2(za, 40); EXF2(zb, 44);
        EXF2(zc, 48); EXF2(zd, 52); EXF2(ze, 56); EXF2(zf, 60);
#undef EXF2

        float* ob = out + (size_t)b * NCLS;
        atomicAdd(ob + 0, pw * a0.x);
        atomicAdd(ob + 1, pw * a0.y);
        atomicAdd(ob + 2, pw * a0.z);
        atomicAdd(ob + 3, pw * a0.w);
        atomicAdd(ob + 4, pw * a1.x);
        atomicAdd(ob + 5, pw * a1.y);
        atomicAdd(ob + 6, pw * a1.z);
        atomicAdd(ob + 7, pw * a1.w);
        atomicAdd(ob + 8, pw * a2.x);
        atomicAdd(ob + 9, pw * a2.y);
    }
}

extern "C" void kernel_launch(void* const* d_in, const int* in_sizes, int n_in,
                              void* d_out, int out_size, void* d_ws, size_t ws_size,
                              hipStream_t stream)
{
    (void)in_sizes; (void)n_in; (void)out_size; (void)ws_size;

    const float* x     = (const float*)d_in[0];
    const int*   uid   = (const int*)  d_in[1];
    const float* bb_w1 = (const float*)d_in[2];
    const float* bb_b1 = (const float*)d_in[3];
    const float* bb_w2 = (const float*)d_in[4];
    const float* bb_b2 = (const float*)d_in[5];
    const float* bb_g  = (const float*)d_in[6];
    const float* bb_be = (const float*)d_in[7];
    const float* gU    = (const float*)d_in[8];
    const float* gV    = (const float*)d_in[9];
    const float* gb    = (const float*)d_in[10];
    const float* e_w1  = (const float*)d_in[11];
    const float* e_b1  = (const float*)d_in[12];
    const float* e_g   = (const float*)d_in[13];
    const float* e_be  = (const float*)d_in[14];
    const float* e_w2  = (const float*)d_in[15];
    const float* e_b2  = (const float*)d_in[16];
    const float* ut    = (const float*)d_in[17];

    float* out = (float*)d_out;
    char*  ws  = (char*)d_ws;

    float* h      = (float*)(ws + OFF_H);
    float* A      = (float*)(ws + OFF_A);
    int*   top_e  = (int*)  (ws + OFF_TOPE);
    float* top_w  = (float*)(ws + OFF_TOPW);
    int*   pair_b = (int*)  (ws + OFF_PAIRB);
    float* pair_w = (float*)(ws + OFF_PAIRW);
    int*   hist   = (int*)  (ws + OFF_HIST);
    int*   offs   = (int*)  (ws + OFF_OFFS);
    int*   cur    = (int*)  (ws + OFF_CUR);

    hipMemsetAsync(out, 0, (size_t)BATCH * NCLS * sizeof(float), stream);
    hipMemsetAsync(hist, 0, NE * sizeof(int), stream);

    k_prep<<<(NUSERS * NE + 255) / 256, 256, 0, stream>>>(gU, gV, ut, A);
    k_fc1<<<BATCH / 256, 256, 0, stream>>>(x, bb_w1, bb_b1, h);
    k_fc2gate<<<BATCH / 256, 256, 0, stream>>>(h, uid, bb_w2, bb_b2, bb_g, bb_be,
                                               A, gb, top_e, top_w, hist);
    k_scan<<<1, 64, 0, stream>>>(hist, offs, cur);
    k_scatter<<<BATCH / 256, 256, 0, stream>>>(top_e, top_w, cur, pair_b, pair_w);
    dim3 eg(EXP_BX, NE);
    k_expert<<<eg, 256, 0, stream>>>(h, pair_b, pair_w, hist, offs,
                                     e_w1, e_b1, e_g, e_be, e_w2, e_b2, out);
}